// Round 3
// baseline (220.623 us; speedup 1.0000x reference)
//
#include <hip/hip_runtime.h>

// out[2i]   = x[2i]
// out[2i+1] = x[2i+1] - x[2i] / 50
// Pure elementwise on adjacent pairs -> memory-bound. float4 = two pairs per
// thread, fully coalesced 16B/lane.
//
// Sizing forensics (rounds 0-2): in_sizes[0] = 33,554,432 (true fp32 element
// count, matches reference 128*64*64*64 and the observed max|N(0,1)|=5.4375);
// out_size = 134,217,728 (4x inflated -- byte count). Rounds 1/2 both ran n4 =
// 33.5M float4s (1.07 GB traffic, 217/219 us @ ~5 TB/s), i.e. 4x overwork with
// OOB reads past the input. Use n = min(in_sizes[0], out_size) = 33,554,432:
// correct under every interpretation, zero OOB, true traffic floor 268 MB.

__global__ __launch_bounds__(256) void dn_kernel(const float4* __restrict__ in,
                                                 float4* __restrict__ out,
                                                 int n4) {
    int i = blockIdx.x * blockDim.x + threadIdx.x;
    if (i < n4) {
        float4 v = in[i];
        float4 r;
        r.x = v.x;
        r.y = v.y - v.x * (1.0f / 50.0f);
        r.z = v.z;
        r.w = v.w - v.z * (1.0f / 50.0f);
        out[i] = r;
    }
}

// Scalar tail (n not divisible by 4) — not expected here, kept for generality.
__global__ void dn_tail_kernel(const float* __restrict__ in,
                               float* __restrict__ out,
                               int start, int n) {
    int i = start + blockIdx.x * blockDim.x + threadIdx.x;
    if (i < n) {
        float v = in[i];
        if (i & 1) {
            out[i] = v - in[i - 1] * (1.0f / 50.0f);
        } else {
            out[i] = v;
        }
    }
}

extern "C" void kernel_launch(void* const* d_in, const int* in_sizes, int n_in,
                              void* d_out, int out_size, void* d_ws, size_t ws_size,
                              hipStream_t stream) {
    const float* in = (const float*)d_in[0];
    float* out = (float*)d_out;

    // True element count: min of the two candidate sizes (see header comment).
    int n = in_sizes[0];
    if (out_size < n) n = out_size;

    int n4 = n / 4;               // 8,388,608 float4s
    if (n4 > 0) {
        int block = 256;
        int grid = (n4 + block - 1) / block;
        dn_kernel<<<grid, block, 0, stream>>>((const float4*)in, (float4*)out, n4);
    }
    int tail_start = n4 * 4;
    if (n - tail_start > 0) {
        dn_tail_kernel<<<1, 64, 0, stream>>>(in, out, tail_start, n);
    }
}